// Round 1
// baseline (139.819 us; speedup 1.0000x reference)
//
#include <hip/hip_runtime.h>
#include <math.h>

#define BD 8
#define SD 1024
#define ID 64
#define OD 128
#define NBD 6

__global__ __launch_bounds__(256) void hier_fused(
    const float* __restrict__ seq,    // (8,1024,64)
    const float* __restrict__ M,      // (128,64)
    const float* __restrict__ P,      // (128,128,6)
    const float* __restrict__ resW,   // (128,64)
    const float* __restrict__ gamma,  // (128)
    const float* __restrict__ beta,   // (128)
    float* __restrict__ out)          // (8,1024,128)
{
    const int s = blockIdx.x;
    const int t = threadIdx.x;

    __shared__ float xs[BD][ID];                   // x[b,s,:]
    __shared__ __align__(16) float xnT[OD][BD];    // x_n transposed: [j][b]
    __shared__ float resid[BD][OD];
    __shared__ float stage[BD][OD];

    // ---- load x[b,s,:] (512 floats) ----
    for (int o = t; o < BD * ID; o += 256) {
        xs[o >> 6][o & 63] = seq[((o >> 6) * SD + s) * ID + (o & 63)];
    }
    __syncthreads();

    // ---- x_t = x@M.T, residual = x@resW.T, LayerNorm ----
    {
        const int b0 = t >> 5;            // 8 groups of 32 threads, one b each
        const int i0 = (t & 31) << 2;     // 4 consecutive i per thread
        float xt[4], rs[4];
        float sum = 0.f, ssq = 0.f;
        #pragma unroll
        for (int o = 0; o < 4; ++o) {
            const int i = i0 + o;
            const float* __restrict__ Mr = &M[i * ID];
            const float* __restrict__ Rr = &resW[i * ID];
            float aM = 0.f, aR = 0.f;
            for (int j = 0; j < ID; ++j) {
                const float xv = xs[b0][j];
                aM = fmaf(xv, Mr[j], aM);
                aR = fmaf(xv, Rr[j], aR);
            }
            xt[o] = aM; rs[o] = aR;
            sum += aM; ssq = fmaf(aM, aM, ssq);
        }
        // reduce across the 32 threads sharing this b (aligned 32-subgroup of a wave)
        #pragma unroll
        for (int m = 1; m < 32; m <<= 1) {
            sum += __shfl_xor(sum, m, 64);
            ssq += __shfl_xor(ssq, m, 64);
        }
        const float mu   = sum * (1.0f / OD);
        const float var  = ssq * (1.0f / OD) - mu * mu;
        const float rstd = rsqrtf(var + 1e-5f);
        #pragma unroll
        for (int o = 0; o < 4; ++o) {
            const int i = i0 + o;
            xnT[i][b0]  = (xt[o] - mu) * rstd * gamma[i] + beta[i];
            resid[b0][i] = rs[o];
        }
    }
    __syncthreads();

    // ---- main: Nk[b,i] = sum_j xn[b,j] * W[i,j],  W on the fly ----
    {
        const int i  = t & 127;
        const int jh = t >> 7;            // j-half: 0 or 1
        float acc[BD];
        #pragma unroll
        for (int b = 0; b < BD; ++b) acc[b] = 0.f;

        const float sf = (float)s;
        const float* __restrict__ Pr = &P[i * (OD * NBD) + jh * 64 * NBD];
        const float pb0 = (float)(i * (OD * NBD) + jh * 64 * NBD + 2);

        for (int j = 0; j < 64; ++j) {
            const int jj = (jh << 6) + j;
            const float pb = pb0 + (float)(j * NBD);
            float w = 0.f;
            #pragma unroll
            for (int g = 0; g < NBD; ++g) {
                const float p  = pb + (float)g;            // exact integer in f32
                const float rp = __builtin_amdgcn_rcpf(p); // 1/p, ~1 ulp
                float fr = sf * rp;                        // revolutions
                fr -= floorf(fr);                          // range-reduce to [0,1)
                // v_cos_f32 takes revolutions: returns cos(2*pi*fr)
                w = fmaf(Pr[j * NBD + g], __builtin_amdgcn_cosf(fr), w);
            }
            const float4 xlo = *(const float4*)&xnT[jj][0];  // broadcast reads
            const float4 xhi = *(const float4*)&xnT[jj][4];
            acc[0] = fmaf(xlo.x, w, acc[0]);
            acc[1] = fmaf(xlo.y, w, acc[1]);
            acc[2] = fmaf(xlo.z, w, acc[2]);
            acc[3] = fmaf(xlo.w, w, acc[3]);
            acc[4] = fmaf(xhi.x, w, acc[4]);
            acc[5] = fmaf(xhi.y, w, acc[5]);
            acc[6] = fmaf(xhi.z, w, acc[6]);
            acc[7] = fmaf(xhi.w, w, acc[7]);
        }

        if (jh) {
            #pragma unroll
            for (int b = 0; b < BD; ++b) stage[b][i] = acc[b];
        }
        __syncthreads();
        if (!jh) {
            #pragma unroll
            for (int b = 0; b < BD; ++b) {
                out[(b * SD + s) * OD + i] = acc[b] + stage[b][i] + resid[b][i];
            }
        }
    }
}

extern "C" void kernel_launch(void* const* d_in, const int* in_sizes, int n_in,
                              void* d_out, int out_size, void* d_ws, size_t ws_size,
                              hipStream_t stream) {
    const float* seq   = (const float*)d_in[0];
    const float* M     = (const float*)d_in[1];
    const float* P     = (const float*)d_in[2];
    const float* resW  = (const float*)d_in[3];
    const float* gamma = (const float*)d_in[4];
    const float* beta  = (const float*)d_in[5];
    float* out = (float*)d_out;

    hier_fused<<<dim3(SD), dim3(256), 0, stream>>>(seq, M, P, resW, gamma, beta, out);
}

// Round 2
// 97.595 us; speedup vs baseline: 1.4326x; 1.4326x over previous
//
#include <hip/hip_runtime.h>
#include <math.h>

#define BD 8
#define SD 1024
#define ID 64
#define OD 128
#define NBD 6

// ---------------- Kernel T: transpose P (i,j,g) -> P2 (j,i,g) ----------------
__global__ __launch_bounds__(256) void p_transpose(
    const float* __restrict__ P, float* __restrict__ P2)
{
    int idx = blockIdx.x * 256 + threadIdx.x;          // 98304 elements
    if (idx >= OD * OD * NBD) return;
    int i = idx / (OD * NBD);
    int r = idx - i * (OD * NBD);
    int j = r / NBD;
    int g = r - j * NBD;
    P2[j * (OD * NBD) + i * NBD + g] = P[idx];
}

// ---------------- Kernel A: x@M.T -> LN -> xn_g ; x@resW.T -> out ------------
__global__ __launch_bounds__(256) void ln_kernel(
    const float* __restrict__ seq,    // (8,1024,64)
    const float* __restrict__ M,      // (128,64)
    const float* __restrict__ resW,   // (128,64)
    const float* __restrict__ gamma,
    const float* __restrict__ beta,
    float* __restrict__ xn_g,         // (1024,128,8)  [s][j][b]
    float* __restrict__ out)          // (8,1024,128)  gets residual
{
    const int s = blockIdx.x;
    const int t = threadIdx.x;
    __shared__ float xs[BD][ID];
    for (int o = t; o < BD * ID; o += 256)
        xs[o >> 6][o & 63] = seq[((o >> 6) * SD + s) * ID + (o & 63)];
    __syncthreads();

    const int b0 = t >> 5;            // 8 groups of 32 threads
    const int i0 = (t & 31) << 2;     // 4 consecutive i
    float xt[4], rs[4];
    float sum = 0.f, ssq = 0.f;
    #pragma unroll
    for (int o = 0; o < 4; ++o) {
        const int i = i0 + o;
        const float* __restrict__ Mr = &M[i * ID];
        const float* __restrict__ Rr = &resW[i * ID];
        float aM = 0.f, aR = 0.f;
        for (int j = 0; j < ID; ++j) {
            const float xv = xs[b0][j];
            aM = fmaf(xv, Mr[j], aM);
            aR = fmaf(xv, Rr[j], aR);
        }
        xt[o] = aM; rs[o] = aR;
        sum += aM; ssq = fmaf(aM, aM, ssq);
    }
    #pragma unroll
    for (int m = 1; m < 32; m <<= 1) {
        sum += __shfl_xor(sum, m, 64);
        ssq += __shfl_xor(ssq, m, 64);
    }
    const float mu   = sum * (1.0f / OD);
    const float var  = ssq * (1.0f / OD) - mu * mu;
    const float rstd = rsqrtf(var + 1e-5f);
    #pragma unroll
    for (int o = 0; o < 4; ++o) {
        const int i = i0 + o;
        xn_g[s * (OD * BD) + i * BD + b0] = (xt[o] - mu) * rstd * gamma[i] + beta[i];
    }
    *(float4*)&out[(b0 * SD + s) * OD + i0] = make_float4(rs[0], rs[1], rs[2], rs[3]);
}

// ---------------- Kernel B: Nk accumulation, out += Nk ----------------------
__global__ __launch_bounds__(256, 8) void nk_kernel(
    const float* __restrict__ P2,     // (128,128,6)  [j][i][g]
    const float* __restrict__ xn_g,   // (1024,128,8) [s][j][b]
    float* __restrict__ out)          // (8,1024,128)
{
    const int s  = blockIdx.x;
    const int ih = blockIdx.y;        // i-half: 0 or 1
    const int t  = threadIdx.x;

    __shared__ __align__(16) float xn[OD][BD];     // 4 KB
    __shared__ float stage[4][ID][BD + 1];         // 9.2 KB, padded

    for (int o = t; o < OD * BD; o += 256)
        ((float*)xn)[o] = xn_g[s * (OD * BD) + o];
    __syncthreads();

    const int il = t & 63;
    const int i  = ih * 64 + il;
    const int jq = t >> 6;            // j-quarter 0..3 (wave-uniform)

    float acc[BD];
    #pragma unroll
    for (int b = 0; b < BD; ++b) acc[b] = 0.f;

    const float sf  = (float)s;
    const float pbI = (float)(i * (OD * NBD) + 2); // base period for this i

    #pragma unroll 2
    for (int j = 0; j < 32; ++j) {
        const int jj = (jq << 5) + j;
        // hoist LDS reads above the trans chain (broadcast, conflict-free)
        const float4 xlo = *(const float4*)&xn[jj][0];
        const float4 xhi = *(const float4*)&xn[jj][4];
        const float* __restrict__ Pr = &P2[jj * (OD * NBD) + i * NBD];
        const float pb = pbI + (float)(jj * NBD);
        float w = 0.f;
        #pragma unroll
        for (int g = 0; g < NBD; ++g) {
            const float p  = pb + (float)g;            // exact int in f32
            const float rp = __builtin_amdgcn_rcpf(p);
            const float fr = __builtin_amdgcn_fractf(sf * rp);
            w = fmaf(Pr[g], __builtin_amdgcn_cosf(fr), w);
        }
        acc[0] = fmaf(xlo.x, w, acc[0]);
        acc[1] = fmaf(xlo.y, w, acc[1]);
        acc[2] = fmaf(xlo.z, w, acc[2]);
        acc[3] = fmaf(xlo.w, w, acc[3]);
        acc[4] = fmaf(xhi.x, w, acc[4]);
        acc[5] = fmaf(xhi.y, w, acc[5]);
        acc[6] = fmaf(xhi.z, w, acc[6]);
        acc[7] = fmaf(xhi.w, w, acc[7]);
    }

    #pragma unroll
    for (int b = 0; b < BD; ++b) stage[jq][il][b] = acc[b];
    __syncthreads();

    for (int idx = t; idx < ID * BD; idx += 256) {
        const int b  = idx >> 6;
        const int ii = idx & 63;
        const float v = stage[0][ii][b] + stage[1][ii][b]
                      + stage[2][ii][b] + stage[3][ii][b];
        out[(b * SD + s) * OD + ih * 64 + ii] += v;
    }
}

extern "C" void kernel_launch(void* const* d_in, const int* in_sizes, int n_in,
                              void* d_out, int out_size, void* d_ws, size_t ws_size,
                              hipStream_t stream) {
    const float* seq   = (const float*)d_in[0];
    const float* M     = (const float*)d_in[1];
    const float* P     = (const float*)d_in[2];
    const float* resW  = (const float*)d_in[3];
    const float* gamma = (const float*)d_in[4];
    const float* beta  = (const float*)d_in[5];
    float* out = (float*)d_out;

    float* xn_g = (float*)d_ws;                    // 4 MB
    float* P2   = xn_g + SD * OD * BD;             // 384 KB

    p_transpose<<<dim3((OD * OD * NBD + 255) / 256), dim3(256), 0, stream>>>(P, P2);
    ln_kernel<<<dim3(SD), dim3(256), 0, stream>>>(seq, M, resW, gamma, beta, xn_g, out);
    nk_kernel<<<dim3(SD, 2), dim3(256), 0, stream>>>(P2, xn_g, out);
}

// Round 3
// 48.433 us; speedup vs baseline: 2.8868x; 2.0150x over previous
//
#include <hip/hip_runtime.h>
#include <math.h>

#define BD 8
#define SD 1024
#define ID 64
#define OD 128
#define NBD 6

// ---------------- Kernel T: transpose P (i,j,g) -> P2 [j][g][i] --------------
__global__ __launch_bounds__(256) void p_transpose(
    const float* __restrict__ P, float* __restrict__ P2)
{
    int idx = blockIdx.x * 256 + threadIdx.x;          // 98304 elements
    if (idx >= OD * OD * NBD) return;
    int i = idx / (OD * NBD);
    int r = idx - i * (OD * NBD);
    int j = r / NBD;
    int g = r - j * NBD;
    P2[(j * NBD + g) * OD + i] = P[idx];
}

// ---------------- Kernel A: weight-stationary proj + LN ---------------------
// 256 threads: i = t&127, mat = t>>7 (0 -> M/LN path, 1 -> residual path).
// Weights live in VGPRs; x is read through wave-uniform addresses (s_load).
#define LNG 2
__global__ __launch_bounds__(256) void ln_kernel(
    const float* __restrict__ seq,    // (8,1024,64)
    const float* __restrict__ M,      // (128,64)
    const float* __restrict__ resW,   // (128,64)
    const float* __restrict__ gamma,
    const float* __restrict__ beta,
    float* __restrict__ xn_g,         // (1024,128,8)  [s][j][b]
    float* __restrict__ out)          // (8,1024,128)  gets residual
{
    const int t   = threadIdx.x;
    const int i   = t & 127;
    const int mat = t >> 7;           // wave-uniform (waves 0,1 = 0; 2,3 = 1)
    __shared__ float red[2][16];

    // ---- stage this thread's weight row into registers (once per block) ----
    float w[ID];
    {
        const float* __restrict__ Wb = (mat ? resW : M) + i * ID;
        #pragma unroll
        for (int c = 0; c < ID / 4; ++c) {
            float4 v = *(const float4*)&Wb[c * 4];
            w[c * 4 + 0] = v.x; w[c * 4 + 1] = v.y;
            w[c * 4 + 2] = v.z; w[c * 4 + 3] = v.w;
        }
    }
    const float gm = gamma[i];
    const float bt = beta[i];

    for (int ls = 0; ls < LNG; ++ls) {
        const int s = blockIdx.x * LNG + ls;

        // ---- acc[b] = dot(x[b,s,:], w) ; x address is wave-uniform --------
        float acc[BD];
        #pragma unroll
        for (int b = 0; b < BD; ++b) {
            const float* __restrict__ xp = &seq[(b * SD + s) * ID];
            float a = 0.f;
            #pragma unroll
            for (int j = 0; j < ID; ++j) a = fmaf(xp[j], w[j], a);
            acc[b] = a;
        }

        // ---- LN stats across the 128 i-lanes (waves 0 & 1 only) -----------
        if (mat == 0) {
            float sum[BD], ssq[BD];
            #pragma unroll
            for (int b = 0; b < BD; ++b) { sum[b] = acc[b]; ssq[b] = acc[b] * acc[b]; }
            #pragma unroll
            for (int m = 1; m < 64; m <<= 1) {
                #pragma unroll
                for (int b = 0; b < BD; ++b) {
                    sum[b] += __shfl_xor(sum[b], m, 64);
                    ssq[b] += __shfl_xor(ssq[b], m, 64);
                }
            }
            if ((t & 63) == 0) {
                const int wv = t >> 6;  // 0 or 1
                #pragma unroll
                for (int b = 0; b < BD; ++b) {
                    red[wv][b]     = sum[b];
                    red[wv][8 + b] = ssq[b];
                }
            }
        }
        __syncthreads();

        if (mat == 0) {
            float xn[BD];
            #pragma unroll
            for (int b = 0; b < BD; ++b) {
                const float sm = red[0][b] + red[1][b];
                const float sq = red[0][8 + b] + red[1][8 + b];
                const float mu = sm * (1.0f / OD);
                const float vr = sq * (1.0f / OD) - mu * mu;
                const float rstd = rsqrtf(vr + 1e-5f);
                xn[b] = (acc[b] - mu) * rstd * gm + bt;
            }
            float* __restrict__ dst = &xn_g[(s * OD + i) * BD];
            *(float4*)&dst[0] = make_float4(xn[0], xn[1], xn[2], xn[3]);
            *(float4*)&dst[4] = make_float4(xn[4], xn[5], xn[6], xn[7]);
        } else {
            #pragma unroll
            for (int b = 0; b < BD; ++b)
                out[(b * SD + s) * OD + i] = acc[b];
        }
        __syncthreads();   // protect red[] for next ls
    }
}

// ---------------- Kernel B: Nk accumulation, out += Nk ----------------------
// 512 threads: il = t&63, jq = t>>6 (8 j-groups of 16). G=4 s per block.
#define NKG 4
__global__ __launch_bounds__(512) void nk_kernel(
    const float* __restrict__ P2,     // [j][g][i]
    const float* __restrict__ xn_g,   // (1024,128,8) [s][j][b]
    float* __restrict__ out)          // (8,1024,128)
{
    const int s0 = blockIdx.x * NKG;
    const int ih = blockIdx.y;
    const int t  = threadIdx.x;
    const int il = t & 63;
    const int i  = ih * 64 + il;
    const int jq = __builtin_amdgcn_readfirstlane(t >> 6);  // wave-uniform

    __shared__ float stage[8][ID][BD + 1];   // 18.4 KB, stride 9 (conflict-free)

    float acc[NKG][BD];
    #pragma unroll
    for (int ls = 0; ls < NKG; ++ls)
        #pragma unroll
        for (int b = 0; b < BD; ++b) acc[ls][b] = 0.f;

    const float pA = (float)(i * (OD * NBD) + 2);

    for (int j = 0; j < 16; ++j) {
        const int jj = jq * 16 + j;
        const float* __restrict__ Pp = &P2[(jj * NBD) * OD + i];  // lane-coalesced
        float Pv[NBD], rp[NBD];
        #pragma unroll
        for (int g = 0; g < NBD; ++g) {
            Pv[g] = Pp[g * OD];
            const float p = pA + (float)(jj * NBD + g);   // exact int in f32
            rp[g] = __builtin_amdgcn_rcpf(p);             // amortized over NKG s
        }
        #pragma unroll
        for (int ls = 0; ls < NKG; ++ls) {
            const float sf = (float)(s0 + ls);
            float wv = 0.f;
            #pragma unroll
            for (int g = 0; g < NBD; ++g) {
                const float fr = __builtin_amdgcn_fractf(sf * rp[g]); // revolutions
                wv = fmaf(Pv[g], __builtin_amdgcn_cosf(fr), wv);      // cos(2*pi*fr)
            }
            // xn address is wave-uniform -> s_load broadcast, no LDS
            const float* __restrict__ xp = &xn_g[((s0 + ls) * OD + jj) * BD];
            #pragma unroll
            for (int b = 0; b < BD; ++b)
                acc[ls][b] = fmaf(xp[b], wv, acc[ls][b]);
        }
    }

    // ---- reduce the 8 jq partials, out += Nk ----
    for (int ls = 0; ls < NKG; ++ls) {
        __syncthreads();
        #pragma unroll
        for (int b = 0; b < BD; ++b) stage[jq][il][b] = acc[ls][b];
        __syncthreads();
        const int il2 = t >> 3;
        const int b2  = t & 7;
        float v = 0.f;
        #pragma unroll
        for (int q = 0; q < 8; ++q) v += stage[q][il2][b2];
        out[(b2 * SD + (s0 + ls)) * OD + ih * 64 + il2] += v;
    }
}

extern "C" void kernel_launch(void* const* d_in, const int* in_sizes, int n_in,
                              void* d_out, int out_size, void* d_ws, size_t ws_size,
                              hipStream_t stream) {
    const float* seq   = (const float*)d_in[0];
    const float* M     = (const float*)d_in[1];
    const float* P     = (const float*)d_in[2];
    const float* resW  = (const float*)d_in[3];
    const float* gamma = (const float*)d_in[4];
    const float* beta  = (const float*)d_in[5];
    float* out = (float*)d_out;

    float* xn_g = (float*)d_ws;                    // 4 MB
    float* P2   = xn_g + SD * OD * BD;             // 384 KB

    p_transpose<<<dim3((OD * OD * NBD + 255) / 256), dim3(256), 0, stream>>>(P, P2);
    ln_kernel<<<dim3(SD / LNG), dim3(256), 0, stream>>>(seq, M, resW, gamma, beta, xn_g, out);
    nk_kernel<<<dim3(SD / NKG, 2), dim3(512), 0, stream>>>(P2, xn_g, out);
}

// Round 4
// 44.712 us; speedup vs baseline: 3.1271x; 1.0832x over previous
//
#include <hip/hip_runtime.h>
#include <math.h>

#define BD 8
#define SD 1024
#define ID 64
#define OD 128
#define NBD 6

// ---------------- Kernel A: weight-stationary proj + LN (+ folded P-transpose)
// 256 threads: i = t&127, mat = t>>7 (0 -> M/LN path, 1 -> residual path).
// Weights live in VGPRs; x is read through wave-uniform addresses (s_load).
__global__ __launch_bounds__(256) void ln_kernel(
    const float* __restrict__ seq,    // (8,1024,64)
    const float* __restrict__ M,      // (128,64)
    const float* __restrict__ resW,   // (128,64)
    const float* __restrict__ gamma,
    const float* __restrict__ beta,
    const float* __restrict__ P,      // (128,128,6) [i][j][g]
    float* __restrict__ P2,           // (128,6,128) [j][g][i]
    float* __restrict__ xn_g,         // (1024,128,8) [s][j][b]
    float* __restrict__ out)          // (8,1024,128)  gets residual
{
    const int t   = threadIdx.x;
    const int s   = blockIdx.x;
    const int i   = t & 127;
    const int mat = t >> 7;           // wave-uniform (waves 0,1 = 0; 2,3 = 1)
    __shared__ float red[2][16];

    // ---- folded P transpose: first 384 blocks move 256 elements each ----
    if (s < (OD * OD * NBD) / 256) {
        const int idx = s * 256 + t;
        const int pi = idx / (OD * NBD);
        const int r  = idx - pi * (OD * NBD);
        const int pj = r / NBD;
        const int pg = r - pj * NBD;
        P2[(pj * NBD + pg) * OD + pi] = P[idx];
    }

    // ---- stage this thread's weight row into registers ----
    float w[ID];
    {
        const float* __restrict__ Wb = (mat ? resW : M) + i * ID;
        #pragma unroll
        for (int c = 0; c < ID / 4; ++c) {
            float4 v = *(const float4*)&Wb[c * 4];
            w[c * 4 + 0] = v.x; w[c * 4 + 1] = v.y;
            w[c * 4 + 2] = v.z; w[c * 4 + 3] = v.w;
        }
    }
    const float gm = gamma[i];
    const float bt = beta[i];

    // ---- acc[b] = dot(x[b,s,:], w); x address wave-uniform -> s_load ----
    float acc[BD];
    #pragma unroll
    for (int b = 0; b < BD; ++b) {
        const float* __restrict__ xp = &seq[(b * SD + s) * ID];
        float a0 = 0.f, a1 = 0.f;          // 2 partial chains for ILP
        #pragma unroll
        for (int j = 0; j < ID; j += 2) {
            a0 = fmaf(xp[j],     w[j],     a0);
            a1 = fmaf(xp[j + 1], w[j + 1], a1);
        }
        acc[b] = a0 + a1;
    }

    // ---- LN stats across 128 i-lanes (waves 0 & 1 only) ----
    if (mat == 0) {
        float sum[BD], ssq[BD];
        #pragma unroll
        for (int b = 0; b < BD; ++b) { sum[b] = acc[b]; ssq[b] = acc[b] * acc[b]; }
        #pragma unroll
        for (int m = 1; m < 64; m <<= 1) {
            #pragma unroll
            for (int b = 0; b < BD; ++b) {
                sum[b] += __shfl_xor(sum[b], m, 64);
                ssq[b] += __shfl_xor(ssq[b], m, 64);
            }
        }
        if ((t & 63) == 0) {
            const int wv = t >> 6;  // 0 or 1
            #pragma unroll
            for (int b = 0; b < BD; ++b) {
                red[wv][b]     = sum[b];
                red[wv][8 + b] = ssq[b];
            }
        }
    }
    __syncthreads();

    if (mat == 0) {
        float xn[BD];
        #pragma unroll
        for (int b = 0; b < BD; ++b) {
            const float sm = red[0][b] + red[1][b];
            const float sq = red[0][8 + b] + red[1][8 + b];
            const float mu = sm * (1.0f / OD);
            const float vr = sq * (1.0f / OD) - mu * mu;
            const float rstd = rsqrtf(vr + 1e-5f);
            xn[b] = (acc[b] - mu) * rstd * gm + bt;
        }
        float* __restrict__ dst = &xn_g[(s * OD + i) * BD];
        *(float4*)&dst[0] = make_float4(xn[0], xn[1], xn[2], xn[3]);
        *(float4*)&dst[4] = make_float4(xn[4], xn[5], xn[6], xn[7]);
    } else {
        #pragma unroll
        for (int b = 0; b < BD; ++b)
            out[(b * SD + s) * OD + i] = acc[b];
    }
}

// ---------------- Kernel B: Nk accumulation, out += Nk ----------------------
// 256 threads: il = t&63 (i-lane), jq = t>>6 = wave id (32 j each). NKG=2 s.
#define NKG 2
__global__ __launch_bounds__(256, 4) void nk_kernel(
    const float* __restrict__ P2,     // [j][g][i]
    const float* __restrict__ xn_g,   // (1024,128,8) [s][j][b]
    float* __restrict__ out)          // (8,1024,128)
{
    const int s0 = blockIdx.x * NKG;
    const int ih = blockIdx.y;
    const int t  = threadIdx.x;
    const int il = t & 63;
    const int i  = ih * 64 + il;
    const int jq = __builtin_amdgcn_readfirstlane(t >> 6);  // wave id, uniform

    __shared__ float stage[4][ID][BD + 1];   // padded: conflict-free

    float acc[NKG][BD];
    #pragma unroll
    for (int ls = 0; ls < NKG; ++ls)
        #pragma unroll
        for (int b = 0; b < BD; ++b) acc[ls][b] = 0.f;

    const float pA = (float)(i * (OD * NBD) + 2);

    #pragma unroll 2
    for (int j = 0; j < 32; ++j) {
        const int jj = (jq << 5) + j;
        const float* __restrict__ Pp = &P2[(jj * NBD) * OD + i];  // lane-coalesced
        float Pv[NBD], rp[NBD];
        #pragma unroll
        for (int g = 0; g < NBD; ++g) {
            Pv[g] = Pp[g * OD];
            const float p = pA + (float)(jj * NBD + g);   // exact int in f32
            rp[g] = __builtin_amdgcn_rcpf(p);
        }
        #pragma unroll
        for (int ls = 0; ls < NKG; ++ls) {
            const float sf = (float)(s0 + ls);
            float wv = 0.f;
            #pragma unroll
            for (int g = 0; g < NBD; ++g) {
                const float fr = __builtin_amdgcn_fractf(sf * rp[g]); // revolutions
                wv = fmaf(Pv[g], __builtin_amdgcn_cosf(fr), wv);      // cos(2*pi*fr)
            }
            // xn address is wave-uniform -> s_load broadcast, no LDS
            const float* __restrict__ xp = &xn_g[((s0 + ls) * OD + jj) * BD];
            #pragma unroll
            for (int b = 0; b < BD; ++b)
                acc[ls][b] = fmaf(xp[b], wv, acc[ls][b]);
        }
    }

    // ---- reduce 4 jq partials, out += Nk ----
    #pragma unroll
    for (int ls = 0; ls < NKG; ++ls) {
        __syncthreads();
        #pragma unroll
        for (int b = 0; b < BD; ++b) stage[jq][il][b] = acc[ls][b];
        __syncthreads();
        #pragma unroll
        for (int o = t; o < ID * BD; o += 256) {
            const int ii = o & 63;
            const int b  = o >> 6;
            const float v = stage[0][ii][b] + stage[1][ii][b]
                          + stage[2][ii][b] + stage[3][ii][b];
            out[(b * SD + (s0 + ls)) * OD + ih * 64 + ii] += v;
        }
    }
}

extern "C" void kernel_launch(void* const* d_in, const int* in_sizes, int n_in,
                              void* d_out, int out_size, void* d_ws, size_t ws_size,
                              hipStream_t stream) {
    const float* seq   = (const float*)d_in[0];
    const float* M     = (const float*)d_in[1];
    const float* P     = (const float*)d_in[2];
    const float* resW  = (const float*)d_in[3];
    const float* gamma = (const float*)d_in[4];
    const float* beta  = (const float*)d_in[5];
    float* out = (float*)d_out;

    float* xn_g = (float*)d_ws;                    // 4 MB
    float* P2   = xn_g + SD * OD * BD;             // 384 KB

    ln_kernel<<<dim3(SD), dim3(256), 0, stream>>>(seq, M, resW, gamma, beta,
                                                  P, P2, xn_g, out);
    nk_kernel<<<dim3(SD / NKG, 2), dim3(256), 0, stream>>>(P2, xn_g, out);
}